// Round 1
// baseline (149.925 us; speedup 1.0000x reference)
//
#include <hip/hip_runtime.h>
#include <hip/hip_bf16.h>

typedef __bf16 bf16x8 __attribute__((ext_vector_type(8)));
typedef __bf16 bf16x4 __attribute__((ext_vector_type(4)));
typedef float  floatx4 __attribute__((ext_vector_type(4)));

#define SD 4096
#define DH 64
#define NB 4

__device__ __forceinline__ float exp2fast(float x) { return __builtin_amdgcn_exp2f(x); }

__device__ __forceinline__ unsigned pack_bf16_2(float a, float b) {
    union { __bf16 h[2]; unsigned u; } cvt;
    cvt.h[0] = (__bf16)a; cvt.h[1] = (__bf16)b;
    return cvt.u;
}

// Pre-pass: K fp32 -> bf16 (same layout); V fp32 -> bf16 transposed VT[b][d][s].
__global__ __launch_bounds__(256) void prep_kernel(const float* __restrict__ k,
                                                   const float* __restrict__ v,
                                                   __bf16* __restrict__ kb,
                                                   __bf16* __restrict__ vt) {
    __shared__ __bf16 tile[64][72];  // pad 72 -> 16B-aligned rows (144B stride)
    const int bid = blockIdx.x;
    const int b = bid >> 6, st = bid & 63;
    const int tid = threadIdx.x;
    const long base = ((long)b * SD + st * 64) * DH;  // element offset of 64x64 chunk

    // K convert: 4096 floats, vectorized
#pragma unroll
    for (int i = 0; i < 4; ++i) {
        int off = tid * 4 + i * 1024;
        float4 f = *(const float4*)(k + base + off);
        bf16x4 o; o[0]=(__bf16)f.x; o[1]=(__bf16)f.y; o[2]=(__bf16)f.z; o[3]=(__bf16)f.w;
        *(bf16x4*)(kb + base + off) = o;
    }
    // V tile load (coalesced) -> LDS transposed
#pragma unroll
    for (int p = 0; p < 4; ++p) {
        int r  = p * 16 + (tid >> 4);
        int dc = (tid & 15) * 4;
        float4 f = *(const float4*)(v + base + r * DH + dc);
        tile[dc+0][r] = (__bf16)f.x;
        tile[dc+1][r] = (__bf16)f.y;
        tile[dc+2][r] = (__bf16)f.z;
        tile[dc+3][r] = (__bf16)f.w;
    }
    __syncthreads();
    // write VT[b][d][st*64 + 0..63], vectorized
    const int d = tid >> 2, seg = tid & 3;
    const long obase = ((long)b * DH + d) * SD + st * 64 + seg * 16;
    bf16x8 w0 = *(const bf16x8*)(&tile[d][seg*16]);
    bf16x8 w1 = *(const bf16x8*)(&tile[d][seg*16+8]);
    *(bf16x8*)(vt + obase)     = w0;
    *(bf16x8*)(vt + obase + 8) = w1;
}

// Flash attention, S^T orientation: scores computed as K·Q^T so softmax
// reductions are in-lane; O accumulated transposed (O^T[d][q]).
__global__ __launch_bounds__(256) void fa_kernel(const float* __restrict__ q,
                                                 const __bf16* __restrict__ kb,
                                                 const __bf16* __restrict__ vt,
                                                 float* __restrict__ out) {
    __shared__ float ldsO[4][64][17];
    __shared__ float ldsM[4][16];
    __shared__ float ldsL[4][16];

    const int tid  = threadIdx.x;
    const int wave = tid >> 6;
    const int lane = tid & 63;
    const int c    = lane & 15;    // column = q index within 16
    const int quad = lane >> 4;
    const int bid   = blockIdx.x;
    const int batch = bid & 3;
    const int j     = bid >> 2;    // 0..63
    const int qsub = wave >> 1;    // which 16-row half of the 32-row tile
    const int kpar = wave & 1;     // key-tile parity split
    const float sc = 0.125f * 1.4426950408889634f;  // scale * log2(e)

    const long qoffB  = (long)batch * SD * DH;
    const long vtoffB = (long)batch * DH * SD;

#pragma unroll
    for (int ti = 0; ti < 2; ++ti) {
        const int T = (ti == 0) ? j : 127 - j;   // paired tiles: constant total work
        const int qbase = T * 32 + qsub * 16;
        const int KT = T / 2 + 1;                // # of 64-key tiles (causal)
        const int qrow = qbase + c;

        // Q fragments (B operand): n = c, k = s*32 + quad*8 + jj
        bf16x8 qf[2];
        {
            const float* qp = q + qoffB + (long)(qbase + c) * DH + quad * 8;
#pragma unroll
            for (int s = 0; s < 2; ++s) {
                float4 f0 = *(const float4*)(qp + s * 32);
                float4 f1 = *(const float4*)(qp + s * 32 + 4);
                bf16x8 t;
                t[0]=(__bf16)f0.x; t[1]=(__bf16)f0.y; t[2]=(__bf16)f0.z; t[3]=(__bf16)f0.w;
                t[4]=(__bf16)f1.x; t[5]=(__bf16)f1.y; t[6]=(__bf16)f1.z; t[7]=(__bf16)f1.w;
                qf[s] = t;
            }
        }

        floatx4 o0 = {0.f,0.f,0.f,0.f}, o1 = o0, o2 = o0, o3 = o0;
        float m = -__builtin_inff(), l = 0.0f;

        for (int kt = kpar; kt < KT; kt += 2) {
            const int kbase = kt * 64;
            // ---- scores S^T[key][q]: A = K (m=key), B = Q (n=q) ----
            floatx4 sa[4];
#pragma unroll
            for (int t = 0; t < 4; ++t) {
                const __bf16* kp = kb + qoffB + (long)(kbase + t*16 + c) * DH + quad * 8;
                bf16x8 kf0 = *(const bf16x8*)(kp);
                bf16x8 kf1 = *(const bf16x8*)(kp + 32);
                floatx4 acc = {0.f,0.f,0.f,0.f};
                acc = __builtin_amdgcn_mfma_f32_16x16x32_bf16(kf0, qf[0], acc, 0, 0, 0);
                acc = __builtin_amdgcn_mfma_f32_16x16x32_bf16(kf1, qf[1], acc, 0, 0, 0);
                sa[t] = acc;
            }
            // ---- mask + scale; softmax state is per-lane (col = q) ----
            float z[16];
#pragma unroll
            for (int t = 0; t < 4; ++t)
#pragma unroll
                for (int r = 0; r < 4; ++r) {
                    int key = kbase + t*16 + quad*4 + r;  // C row = key_local
                    float val = sa[t][r] * sc;
                    z[t*4+r] = (key <= qrow) ? val : -__builtin_inff();
                }
            float zmax = z[0];
#pragma unroll
            for (int i = 1; i < 16; ++i) zmax = fmaxf(zmax, z[i]);
            zmax = fmaxf(zmax, __shfl_xor(zmax, 16));
            zmax = fmaxf(zmax, __shfl_xor(zmax, 32));
            const float mn = fmaxf(m, zmax);
            const float alpha = exp2fast(m - mn);
            float p[16];
            float rs = 0.0f;
#pragma unroll
            for (int i = 0; i < 16; ++i) { p[i] = exp2fast(z[i] - mn); rs += p[i]; }
            rs += __shfl_xor(rs, 16);
            rs += __shfl_xor(rs, 32);
            l = l * alpha + rs;
            m = mn;
            o0 *= alpha; o1 *= alpha; o2 *= alpha; o3 *= alpha;

            // ---- P^T (C layout) -> B-operand layout via packed shuffles ----
            unsigned pk[4][2];
#pragma unroll
            for (int t = 0; t < 4; ++t) {
                pk[t][0] = pack_bf16_2(p[t*4+0], p[t*4+1]);
                pk[t][1] = pack_bf16_2(p[t*4+2], p[t*4+3]);
            }
            const int selhi = quad >> 1;
            const int q1 = quad & 1;
#pragma unroll
            for (int s = 0; s < 2; ++s) {
                unsigned bb[4];
#pragma unroll
                for (int jj = 0; jj < 4; ++jj) {
                    int srcl = ((2*q1 + (jj >> 1)) << 4) | c;
                    unsigned v0 = (unsigned)__shfl((int)pk[2*s + 0][jj & 1], srcl);
                    unsigned v1 = (unsigned)__shfl((int)pk[2*s + 1][jj & 1], srcl);
                    bb[jj] = selhi ? v1 : v0;
                }
                union { unsigned u[4]; bf16x8 f; } bp;
                bp.u[0]=bb[0]; bp.u[1]=bb[1]; bp.u[2]=bb[2]; bp.u[3]=bb[3];
                // ---- O^T[d][q] += V^T · P^T : A = V^T (m=d), B = P^T (n=q) ----
                const __bf16* vp = vt + vtoffB + (long)c * SD + kbase + s*32 + quad*8;
                bf16x8 vf0 = *(const bf16x8*)(vp);
                bf16x8 vf1 = *(const bf16x8*)(vp + 16L*SD);
                bf16x8 vf2 = *(const bf16x8*)(vp + 32L*SD);
                bf16x8 vf3 = *(const bf16x8*)(vp + 48L*SD);
                o0 = __builtin_amdgcn_mfma_f32_16x16x32_bf16(vf0, bp.f, o0, 0, 0, 0);
                o1 = __builtin_amdgcn_mfma_f32_16x16x32_bf16(vf1, bp.f, o1, 0, 0, 0);
                o2 = __builtin_amdgcn_mfma_f32_16x16x32_bf16(vf2, bp.f, o2, 0, 0, 0);
                o3 = __builtin_amdgcn_mfma_f32_16x16x32_bf16(vf3, bp.f, o3, 0, 0, 0);
            }
        }

        // ---- write partials; combine key-parity waves; store ----
#pragma unroll
        for (int dt = 0; dt < 4; ++dt) {
            floatx4 ov = (dt==0)?o0:(dt==1)?o1:(dt==2)?o2:o3;
#pragma unroll
            for (int r = 0; r < 4; ++r) {
                int d = dt*16 + quad*4 + r;
                ldsO[wave][d][c] = ov[r];
            }
        }
        if (quad == 0) { ldsM[wave][c] = m; ldsL[wave][c] = l; }
        __syncthreads();
#pragma unroll
        for (int i = 0; i < 8; ++i) {
            int oidx = tid + 256*i;          // 2048 outputs for this 32-row tile
            int d  = oidx & 63;
            int qq = oidx >> 6;              // 0..31
            int qs = qq >> 4, cc = qq & 15;
            int w0 = qs*2, w1 = qs*2 + 1;
            float m0 = ldsM[w0][cc], m1 = ldsM[w1][cc];
            float l0 = ldsL[w0][cc], l1 = ldsL[w1][cc];
            float ms = fmaxf(m0, m1);
            float c0 = exp2fast(m0 - ms), c1 = exp2fast(m1 - ms);
            float denom = c0*l0 + c1*l1;
            float val = (c0*ldsO[w0][d][cc] + c1*ldsO[w1][d][cc]) / denom;
            out[qoffB + (long)(T*32 + qq) * DH + d] = val;
        }
        __syncthreads();
    }
}

extern "C" void kernel_launch(void* const* d_in, const int* in_sizes, int n_in,
                              void* d_out, int out_size, void* d_ws, size_t ws_size,
                              hipStream_t stream) {
    const float* q = (const float*)d_in[0];
    const float* k = (const float*)d_in[1];
    const float* v = (const float*)d_in[2];
    float* out = (float*)d_out;
    __bf16* kb  = (__bf16*)d_ws;
    __bf16* vtb = kb + (size_t)NB * SD * DH;   // 2MB each, 4MB total in ws
    prep_kernel<<<dim3(256), dim3(256), 0, stream>>>(k, v, kb, vtb);
    fa_kernel<<<dim3(256), dim3(256), 0, stream>>>(q, kb, vtb, out);
}

// Round 2
// 142.207 us; speedup vs baseline: 1.0543x; 1.0543x over previous
//
#include <hip/hip_runtime.h>
#include <hip/hip_bf16.h>

typedef __bf16 bf16x8 __attribute__((ext_vector_type(8)));
typedef __bf16 bf16x4 __attribute__((ext_vector_type(4)));
typedef float  floatx4 __attribute__((ext_vector_type(4)));

#define SD 4096
#define DH 64
#define NB 4

__device__ __forceinline__ float exp2fast(float x) { return __builtin_amdgcn_exp2f(x); }

__device__ __forceinline__ unsigned pack_bf16_2(float a, float b) {
    union { __bf16 h[2]; unsigned u; } cvt;
    cvt.h[0] = (__bf16)a; cvt.h[1] = (__bf16)b;
    return cvt.u;
}

// Pre-pass: K fp32 -> bf16 (same layout); V fp32 -> bf16 transposed VT[b][d][s].
// 1024 blocks, each a 16(seq) x 64(d) chunk -> 4 blocks/CU.
__global__ __launch_bounds__(256) void prep_kernel(const float* __restrict__ k,
                                                   const float* __restrict__ v,
                                                   __bf16* __restrict__ kb,
                                                   __bf16* __restrict__ vt) {
    __shared__ __bf16 tile[64][24];  // [d][seq], padded
    const int bid = blockIdx.x;
    const int b = bid >> 8, st = bid & 255;   // 16-row chunk index
    const int tid = threadIdx.x;
    const long base = ((long)b * SD + st * 16) * DH;

    // K convert: 1024 floats -> one float4 per thread
    {
        int off = tid * 4;
        float4 f = *(const float4*)(k + base + off);
        bf16x4 o; o[0]=(__bf16)f.x; o[1]=(__bf16)f.y; o[2]=(__bf16)f.z; o[3]=(__bf16)f.w;
        *(bf16x4*)(kb + base + off) = o;
    }
    // V tile load (coalesced) -> LDS transposed
    {
        int r  = tid >> 4;            // 0..15 seq row
        int dc = (tid & 15) * 4;      // d column
        float4 f = *(const float4*)(v + base + r * DH + dc);
        tile[dc+0][r] = (__bf16)f.x;
        tile[dc+1][r] = (__bf16)f.y;
        tile[dc+2][r] = (__bf16)f.z;
        tile[dc+3][r] = (__bf16)f.w;
    }
    __syncthreads();
    // write VT[b][d][st*16 + 0..15]
    const int d = tid >> 2, seg = tid & 3;
    const long obase = ((long)b * DH + d) * SD + st * 16 + seg * 4;
    *(bf16x4*)(vt + obase) = *(const bf16x4*)(&tile[d][seg * 4]);
}

// Flash attention, S^T orientation: scores computed as K·Q^T so softmax
// reductions are in-lane; O accumulated transposed (O^T[d][q]).
// One 16-row Q tile per block; 4 waves split key tiles 4-way; LDS combine.
__global__ __launch_bounds__(256) void fa_kernel(const float* __restrict__ q,
                                                 const __bf16* __restrict__ kb,
                                                 const __bf16* __restrict__ vt,
                                                 float* __restrict__ out) {
    __shared__ float ldsO[4][64][17];
    __shared__ float ldsM[4][16];
    __shared__ float ldsL[4][16];

    const int tid  = threadIdx.x;
    const int wave = tid >> 6;
    const int lane = tid & 63;
    const int c    = lane & 15;    // column = q index within 16
    const int quad = lane >> 4;
    const int bid   = blockIdx.x;
    const int batch = bid & 3;
    const int T     = 255 - (bid >> 2);   // big (causal-long) tiles dispatch first
    const float sc = 0.125f * 1.4426950408889634f;  // scale * log2(e)

    const long qoffB  = (long)batch * SD * DH;
    const long vtoffB = (long)batch * DH * SD;

    const int qbase = T * 16;
    const int KT = T / 4 + 1;          // # of 64-key tiles (causal)
    const int qrow = qbase + c;

    // Q fragments (B operand): n = c, k = s*32 + quad*8 + jj
    bf16x8 qf[2];
    {
        const float* qp = q + qoffB + (long)(qbase + c) * DH + quad * 8;
#pragma unroll
        for (int s = 0; s < 2; ++s) {
            float4 f0 = *(const float4*)(qp + s * 32);
            float4 f1 = *(const float4*)(qp + s * 32 + 4);
            bf16x8 t;
            t[0]=(__bf16)f0.x; t[1]=(__bf16)f0.y; t[2]=(__bf16)f0.z; t[3]=(__bf16)f0.w;
            t[4]=(__bf16)f1.x; t[5]=(__bf16)f1.y; t[6]=(__bf16)f1.z; t[7]=(__bf16)f1.w;
            qf[s] = t;
        }
    }

    floatx4 o0 = {0.f,0.f,0.f,0.f}, o1 = o0, o2 = o0, o3 = o0;
    float m = -__builtin_inff(), l = 0.0f;

    for (int kt = wave; kt < KT; kt += 4) {
        const int kbase = kt * 64;
        // ---- scores S^T[key][q]: A = K (m=key), B = Q (n=q) ----
        floatx4 sa[4];
#pragma unroll
        for (int t = 0; t < 4; ++t) {
            const __bf16* kp = kb + qoffB + (long)(kbase + t*16 + c) * DH + quad * 8;
            bf16x8 kf0 = *(const bf16x8*)(kp);
            bf16x8 kf1 = *(const bf16x8*)(kp + 32);
            floatx4 acc = {0.f,0.f,0.f,0.f};
            acc = __builtin_amdgcn_mfma_f32_16x16x32_bf16(kf0, qf[0], acc, 0, 0, 0);
            acc = __builtin_amdgcn_mfma_f32_16x16x32_bf16(kf1, qf[1], acc, 0, 0, 0);
            sa[t] = acc;
        }
        // ---- mask + scale; softmax state is per-lane (col = q) ----
        float z[16];
#pragma unroll
        for (int t = 0; t < 4; ++t)
#pragma unroll
            for (int r = 0; r < 4; ++r) {
                int key = kbase + t*16 + quad*4 + r;  // C row = key_local
                float val = sa[t][r] * sc;
                z[t*4+r] = (key <= qrow) ? val : -__builtin_inff();
            }
        float zmax = z[0];
#pragma unroll
        for (int i = 1; i < 16; ++i) zmax = fmaxf(zmax, z[i]);
        zmax = fmaxf(zmax, __shfl_xor(zmax, 16));
        zmax = fmaxf(zmax, __shfl_xor(zmax, 32));
        const float mn = fmaxf(m, zmax);
        const float alpha = exp2fast(m - mn);
        float p[16];
        float rs = 0.0f;
#pragma unroll
        for (int i = 0; i < 16; ++i) { p[i] = exp2fast(z[i] - mn); rs += p[i]; }
        rs += __shfl_xor(rs, 16);
        rs += __shfl_xor(rs, 32);
        l = l * alpha + rs;
        m = mn;
        o0 *= alpha; o1 *= alpha; o2 *= alpha; o3 *= alpha;

        // ---- P^T (C layout) -> B-operand layout via packed shuffles ----
        unsigned pk[4][2];
#pragma unroll
        for (int t = 0; t < 4; ++t) {
            pk[t][0] = pack_bf16_2(p[t*4+0], p[t*4+1]);
            pk[t][1] = pack_bf16_2(p[t*4+2], p[t*4+3]);
        }
        const int selhi = quad >> 1;
        const int q1 = quad & 1;
#pragma unroll
        for (int s = 0; s < 2; ++s) {
            unsigned bb[4];
#pragma unroll
            for (int jj = 0; jj < 4; ++jj) {
                int srcl = ((2*q1 + (jj >> 1)) << 4) | c;
                unsigned v0 = (unsigned)__shfl((int)pk[2*s + 0][jj & 1], srcl);
                unsigned v1 = (unsigned)__shfl((int)pk[2*s + 1][jj & 1], srcl);
                bb[jj] = selhi ? v1 : v0;
            }
            union { unsigned u[4]; bf16x8 f; } bp;
            bp.u[0]=bb[0]; bp.u[1]=bb[1]; bp.u[2]=bb[2]; bp.u[3]=bb[3];
            // ---- O^T[d][q] += V^T · P^T : A = V^T (m=d), B = P^T (n=q) ----
            const __bf16* vp = vt + vtoffB + (long)c * SD + kbase + s*32 + quad*8;
            bf16x8 vf0 = *(const bf16x8*)(vp);
            bf16x8 vf1 = *(const bf16x8*)(vp + 16L*SD);
            bf16x8 vf2 = *(const bf16x8*)(vp + 32L*SD);
            bf16x8 vf3 = *(const bf16x8*)(vp + 48L*SD);
            o0 = __builtin_amdgcn_mfma_f32_16x16x32_bf16(vf0, bp.f, o0, 0, 0, 0);
            o1 = __builtin_amdgcn_mfma_f32_16x16x32_bf16(vf1, bp.f, o1, 0, 0, 0);
            o2 = __builtin_amdgcn_mfma_f32_16x16x32_bf16(vf2, bp.f, o2, 0, 0, 0);
            o3 = __builtin_amdgcn_mfma_f32_16x16x32_bf16(vf3, bp.f, o3, 0, 0, 0);
        }
    }

    // ---- write partials; combine the 4 key-split waves; store ----
#pragma unroll
    for (int dt = 0; dt < 4; ++dt) {
        floatx4 ov = (dt==0)?o0:(dt==1)?o1:(dt==2)?o2:o3;
#pragma unroll
        for (int r = 0; r < 4; ++r) {
            int d = dt*16 + quad*4 + r;
            ldsO[wave][d][c] = ov[r];
        }
    }
    if (quad == 0) { ldsM[wave][c] = m; ldsL[wave][c] = l; }
    __syncthreads();
#pragma unroll
    for (int i = 0; i < 4; ++i) {
        int oidx = tid + 256*i;          // 1024 outputs for this 16-row tile
        int d  = oidx & 63;
        int qq = oidx >> 6;              // 0..15
        float m0 = ldsM[0][qq], m1 = ldsM[1][qq], m2 = ldsM[2][qq], m3 = ldsM[3][qq];
        float ms = fmaxf(fmaxf(m0, m1), fmaxf(m2, m3));
        float c0 = exp2fast(m0 - ms), c1 = exp2fast(m1 - ms);
        float c2 = exp2fast(m2 - ms), c3 = exp2fast(m3 - ms);
        float denom = c0*ldsL[0][qq] + c1*ldsL[1][qq] + c2*ldsL[2][qq] + c3*ldsL[3][qq];
        float num = c0*ldsO[0][d][qq] + c1*ldsO[1][d][qq]
                  + c2*ldsO[2][d][qq] + c3*ldsO[3][d][qq];
        out[qoffB + (long)(qbase + qq) * DH + d] = num / denom;
    }
}

extern "C" void kernel_launch(void* const* d_in, const int* in_sizes, int n_in,
                              void* d_out, int out_size, void* d_ws, size_t ws_size,
                              hipStream_t stream) {
    const float* q = (const float*)d_in[0];
    const float* k = (const float*)d_in[1];
    const float* v = (const float*)d_in[2];
    float* out = (float*)d_out;
    __bf16* kb  = (__bf16*)d_ws;
    __bf16* vtb = kb + (size_t)NB * SD * DH;   // 2MB each, 4MB total in ws
    prep_kernel<<<dim3(1024), dim3(256), 0, stream>>>(k, v, kb, vtb);
    fa_kernel<<<dim3(1024), dim3(256), 0, stream>>>(q, kb, vtb, out);
}

// Round 3
// 130.872 us; speedup vs baseline: 1.1456x; 1.0866x over previous
//
#include <hip/hip_runtime.h>
#include <hip/hip_bf16.h>

typedef __bf16 bf16x8 __attribute__((ext_vector_type(8)));
typedef __bf16 bf16x4 __attribute__((ext_vector_type(4)));
typedef float  floatx4 __attribute__((ext_vector_type(4)));

#define SD 4096
#define DH 64
#define NB 4

__device__ __forceinline__ float exp2fast(float x) { return __builtin_amdgcn_exp2f(x); }

__device__ __forceinline__ unsigned pack_bf16_2(float a, float b) {
    union { __bf16 h[2]; unsigned u; } cvt;
    cvt.h[0] = (__bf16)a; cvt.h[1] = (__bf16)b;
    return cvt.u;
}

// Pre-pass: K fp32 -> bf16 (same layout); V fp32 -> bf16 transposed VT[b][d][s].
__global__ __launch_bounds__(256) void prep_kernel(const float* __restrict__ k,
                                                   const float* __restrict__ v,
                                                   __bf16* __restrict__ kb,
                                                   __bf16* __restrict__ vt) {
    __shared__ __bf16 tile[64][24];
    const int bid = blockIdx.x;
    const int b = bid >> 8, st = bid & 255;
    const int tid = threadIdx.x;
    const long base = ((long)b * SD + st * 16) * DH;

    {
        int off = tid * 4;
        float4 f = *(const float4*)(k + base + off);
        bf16x4 o; o[0]=(__bf16)f.x; o[1]=(__bf16)f.y; o[2]=(__bf16)f.z; o[3]=(__bf16)f.w;
        *(bf16x4*)(kb + base + off) = o;
    }
    {
        int r  = tid >> 4;
        int dc = (tid & 15) * 4;
        float4 f = *(const float4*)(v + base + r * DH + dc);
        tile[dc+0][r] = (__bf16)f.x;
        tile[dc+1][r] = (__bf16)f.y;
        tile[dc+2][r] = (__bf16)f.z;
        tile[dc+3][r] = (__bf16)f.w;
    }
    __syncthreads();
    const int d = tid >> 2, seg = tid & 3;
    const long obase = ((long)b * DH + d) * SD + st * 16 + seg * 4;
    *(bf16x4*)(vt + obase) = *(const bf16x4*)(&tile[d][seg * 4]);
}

// Flash attention, S^T orientation. One block = PAIR of 16-row Q tiles
// {TA=p, TB=255-p} -> exactly 65 key-tile jobs per block (perfect balance).
// 8 waves split jobs 8-way; each wave holds both tiles' softmax states.
__global__ __launch_bounds__(512, 4) void fa_kernel(const float* __restrict__ q,
                                                    const __bf16* __restrict__ kb,
                                                    const __bf16* __restrict__ vt,
                                                    float* __restrict__ out) {
    __shared__ float ldsO[8 * 1089];   // [w]*1089 + d*17 + c  (1089 % 32 == 1: conflict-free layer stride)
    __shared__ float ldsM[8][16];
    __shared__ float ldsL[8][16];

    const int tid  = threadIdx.x;
    const int wave = tid >> 6;       // 0..7
    const int lane = tid & 63;
    const int c    = lane & 15;      // q column within 16
    const int quad = lane >> 4;
    const int bid   = blockIdx.x;
    const int batch = bid & 3;
    const int pr    = bid >> 2;      // pair index 0..127
    const float sc = 0.125f * 1.4426950408889634f;   // scale * log2(e), folded into Q

    const long offB   = (long)batch * SD * DH;
    const long vtoffB = (long)batch * DH * SD;

    const int TA = pr, TB = 255 - pr;
    const int LA = (TA >> 2) + 1, LB = (TB >> 2) + 1;   // LA + LB == 65

    // Q fragments for both tiles (B operand): n=c, k=s*32+quad*8+j, pre-scaled.
    bf16x8 qfA[2], qfB[2];
#pragma unroll
    for (int which = 0; which < 2; ++which) {
        const int qbase = (which == 0 ? TA : TB) * 16;
        const float* qp = q + offB + (long)(qbase + c) * DH + quad * 8;
        bf16x8* dst = which == 0 ? qfA : qfB;
#pragma unroll
        for (int s = 0; s < 2; ++s) {
            float4 f0 = *(const float4*)(qp + s * 32);
            float4 f1 = *(const float4*)(qp + s * 32 + 4);
            bf16x8 t;
            t[0]=(__bf16)(f0.x*sc); t[1]=(__bf16)(f0.y*sc); t[2]=(__bf16)(f0.z*sc); t[3]=(__bf16)(f0.w*sc);
            t[4]=(__bf16)(f1.x*sc); t[5]=(__bf16)(f1.y*sc); t[6]=(__bf16)(f1.z*sc); t[7]=(__bf16)(f1.w*sc);
            dst[s] = t;
        }
    }

    floatx4 oA[4], oB[4];
#pragma unroll
    for (int i = 0; i < 4; ++i) { oA[i] = (floatx4){0.f,0.f,0.f,0.f}; oB[i] = oA[i]; }
    float mA = -__builtin_inff(), lA = 0.0f;
    float mB = -__builtin_inff(), lB = 0.0f;

    // One 64-key job. masked=true only for the diagonal tile (wave-uniform).
    auto job = [&](int kt, const bf16x8* qf, floatx4* o, float& m, float& l,
                   bool masked, int qrow) {
        const int kbase = kt * 64;
        // scores S^T[key][q]: A = K, B = Q
        bf16x8 kf[4][2];
#pragma unroll
        for (int t = 0; t < 4; ++t) {
            const __bf16* kp = kb + offB + (long)(kbase + t*16 + c) * DH + quad * 8;
            kf[t][0] = *(const bf16x8*)(kp);
            kf[t][1] = *(const bf16x8*)(kp + 32);
        }
        floatx4 sa[4];
#pragma unroll
        for (int t = 0; t < 4; ++t) {
            floatx4 acc = {0.f,0.f,0.f,0.f};
            acc = __builtin_amdgcn_mfma_f32_16x16x32_bf16(kf[t][0], qf[0], acc, 0, 0, 0);
            acc = __builtin_amdgcn_mfma_f32_16x16x32_bf16(kf[t][1], qf[1], acc, 0, 0, 0);
            sa[t] = acc;
        }
        float z[16];
        if (masked) {
#pragma unroll
            for (int t = 0; t < 4; ++t)
#pragma unroll
                for (int r = 0; r < 4; ++r) {
                    int key = kbase + t*16 + quad*4 + r;
                    z[t*4+r] = (key <= qrow) ? sa[t][r] : -__builtin_inff();
                }
        } else {
#pragma unroll
            for (int t = 0; t < 4; ++t)
#pragma unroll
                for (int r = 0; r < 4; ++r) z[t*4+r] = sa[t][r];
        }
        // tree max (depth 4) + cross-quad
        float x8[8], x4v[4], x2v[2];
#pragma unroll
        for (int i = 0; i < 8; ++i) x8[i] = fmaxf(z[i], z[i+8]);
#pragma unroll
        for (int i = 0; i < 4; ++i) x4v[i] = fmaxf(x8[i], x8[i+4]);
        x2v[0] = fmaxf(x4v[0], x4v[2]); x2v[1] = fmaxf(x4v[1], x4v[3]);
        float zmax = fmaxf(x2v[0], x2v[1]);
        zmax = fmaxf(zmax, __shfl_xor(zmax, 16));
        zmax = fmaxf(zmax, __shfl_xor(zmax, 32));
        const float mn = fmaxf(m, zmax);
        const float alpha = exp2fast(m - mn);
        float pe[16];
#pragma unroll
        for (int i = 0; i < 16; ++i) pe[i] = exp2fast(z[i] - mn);
        float s8[8], s4v[4];
#pragma unroll
        for (int i = 0; i < 8; ++i) s8[i] = pe[i] + pe[i+8];
#pragma unroll
        for (int i = 0; i < 4; ++i) s4v[i] = s8[i] + s8[i+4];
        float rs = (s4v[0] + s4v[2]) + (s4v[1] + s4v[3]);
        rs += __shfl_xor(rs, 16);
        rs += __shfl_xor(rs, 32);
        l = l * alpha + rs;
        m = mn;
#pragma unroll
        for (int i = 0; i < 4; ++i) o[i] *= alpha;

        // P^T (C layout) -> B operand via packed shuffles
        unsigned pk4[4][2];
#pragma unroll
        for (int t = 0; t < 4; ++t) {
            pk4[t][0] = pack_bf16_2(pe[t*4+0], pe[t*4+1]);
            pk4[t][1] = pack_bf16_2(pe[t*4+2], pe[t*4+3]);
        }
        const int selhi = quad >> 1;
        const int q1 = quad & 1;
#pragma unroll
        for (int s = 0; s < 2; ++s) {
            unsigned bb[4];
#pragma unroll
            for (int jj = 0; jj < 4; ++jj) {
                int srcl = ((2*q1 + (jj >> 1)) << 4) | c;
                unsigned v0 = (unsigned)__shfl((int)pk4[2*s + 0][jj & 1], srcl);
                unsigned v1 = (unsigned)__shfl((int)pk4[2*s + 1][jj & 1], srcl);
                bb[jj] = selhi ? v1 : v0;
            }
            union { unsigned u[4]; bf16x8 f; } bp;
            bp.u[0]=bb[0]; bp.u[1]=bb[1]; bp.u[2]=bb[2]; bp.u[3]=bb[3];
            const __bf16* vp = vt + vtoffB + (long)c * SD + kbase + s*32 + quad*8;
            bf16x8 vf0 = *(const bf16x8*)(vp);
            bf16x8 vf1 = *(const bf16x8*)(vp + 16L*SD);
            bf16x8 vf2 = *(const bf16x8*)(vp + 32L*SD);
            bf16x8 vf3 = *(const bf16x8*)(vp + 48L*SD);
            o[0] = __builtin_amdgcn_mfma_f32_16x16x32_bf16(vf0, bp.f, o[0], 0, 0, 0);
            o[1] = __builtin_amdgcn_mfma_f32_16x16x32_bf16(vf1, bp.f, o[1], 0, 0, 0);
            o[2] = __builtin_amdgcn_mfma_f32_16x16x32_bf16(vf2, bp.f, o[2], 0, 0, 0);
            o[3] = __builtin_amdgcn_mfma_f32_16x16x32_bf16(vf3, bp.f, o[3], 0, 0, 0);
        }
    };

    // tile A jobs (stride 8 over waves); diagonal tile peeled with mask
    {
        const int KTm1 = LA - 1;
        int kt = wave;
        for (; kt < KTm1; kt += 8) job(kt, qfA, oA, mA, lA, false, 0);
        if (kt == KTm1) job(kt, qfA, oA, mA, lA, true, TA*16 + c);
    }
    // tile B jobs
    {
        const int KTm1 = LB - 1;
        int kt = (wave - LA) & 7;
        for (; kt < KTm1; kt += 8) job(kt, qfB, oB, mB, lB, false, 0);
        if (kt == KTm1) job(kt, qfB, oB, mB, lB, true, TB*16 + c);
    }

    // ---- two-phase combine: A then B (reusing the same LDS) ----
#pragma unroll
    for (int phase = 0; phase < 2; ++phase) {
        const floatx4* o = phase == 0 ? oA : oB;
        const float m = phase == 0 ? mA : mB;
        const float l = phase == 0 ? lA : lB;
        const int qbase = (phase == 0 ? TA : TB) * 16;
        if (phase == 1) __syncthreads();   // protect LDS reuse (WAR vs phase-0 reads)
#pragma unroll
        for (int dt = 0; dt < 4; ++dt)
#pragma unroll
            for (int r = 0; r < 4; ++r)
                ldsO[wave*1089 + (dt*16 + quad*4 + r)*17 + c] = o[dt][r];
        if (quad == 0) { ldsM[wave][c] = m; ldsL[wave][c] = l; }
        __syncthreads();
#pragma unroll
        for (int i = 0; i < 2; ++i) {
            int oidx = tid + 512*i;       // 1024 outputs
            int d  = oidx & 63;
            int qq = oidx >> 6;
            float mw[8];
#pragma unroll
            for (int w = 0; w < 8; ++w) mw[w] = ldsM[w][qq];
            float ms = fmaxf(fmaxf(fmaxf(mw[0],mw[1]),fmaxf(mw[2],mw[3])),
                             fmaxf(fmaxf(mw[4],mw[5]),fmaxf(mw[6],mw[7])));
            float num = 0.f, den = 0.f;
#pragma unroll
            for (int w = 0; w < 8; ++w) {
                float cw = exp2fast(mw[w] - ms);
                den += cw * ldsL[w][qq];
                num += cw * ldsO[w*1089 + d*17 + qq];
            }
            out[offB + (long)(qbase + qq) * DH + d] = num / den;
        }
    }
}

extern "C" void kernel_launch(void* const* d_in, const int* in_sizes, int n_in,
                              void* d_out, int out_size, void* d_ws, size_t ws_size,
                              hipStream_t stream) {
    const float* q = (const float*)d_in[0];
    const float* k = (const float*)d_in[1];
    const float* v = (const float*)d_in[2];
    float* out = (float*)d_out;
    __bf16* kb  = (__bf16*)d_ws;
    __bf16* vtb = kb + (size_t)NB * SD * DH;
    prep_kernel<<<dim3(1024), dim3(256), 0, stream>>>(k, v, kb, vtb);
    fa_kernel<<<dim3(512), dim3(512), 0, stream>>>(q, kb, vtb, out);
}